// Round 4
// baseline (509.721 us; speedup 1.0000x reference)
//
#include <hip/hip_runtime.h>

// OSQP batched ADMM, B=256 N=128 M=192, 400 iters.
// R4: R3 structure (validated); loop kernel issue-count attack:
//   - explicit v_pk_fma_f32 / v_pk_mul_f32 (compiler was scalarizing v2f math)
//   - DPP reduction fused to v_add_f32_dpp (old = x, no zero-init mov)
//   - producer chain: s_new = rho*(2z - v) written before y/Sacc updates
// Algebra: M = P + sI + rho*AtA (SPD);  Wt = A*Minv;  c = Minv q
//   V = A Minv At;  d = A c
//   iterate (s_0=0): t = V s - d ; zc = a*t+(1-a)z ; v = zc + y/rho ;
//     z = clip(v,l,u) ; y = rho*(v-z) ; Sacc = (1-a)Sacc + a*s ; s = rho*z - y
//   epilogue: x = Wt^T Sacc - c

#define Nn 128
#define Mm 192
constexpr float RHO_    = 0.1f;
constexpr float RHOINV_ = 10.0f;
constexpr float SIGMA_  = 1e-6f;
constexpr float ALPHA_  = 1.6f;
constexpr int   NITERS_ = 400;

typedef float v2f __attribute__((ext_vector_type(2)));
typedef float v4f __attribute__((ext_vector_type(4)));

__device__ __forceinline__ v2f pk_mul(v2f a, v2f b) {
  v2f d; asm("v_pk_mul_f32 %0, %1, %2" : "=v"(d) : "v"(a), "v"(b)); return d;
}
__device__ __forceinline__ v2f pk_fma(v2f a, v2f b, v2f c) {
  v2f d; asm("v_pk_fma_f32 %0, %1, %2, %3" : "=v"(d) : "v"(a), "v"(b), "v"(c)); return d;
}

template<int CTRL>
__device__ __forceinline__ float dpp_add(float x) {
  // old = x so LLVM can fold to v_add_f32_dpp (no zero-init mov)
  int y = __builtin_amdgcn_update_dpp(__float_as_int(x), __float_as_int(x),
                                      CTRL, 0xF, 0xF, false);
  return x + __int_as_float(y);
}
// sum across aligned 16-lane group: row_ror 1,2,4,8
__device__ __forceinline__ float red16(float x) {
  x = dpp_add<0x121>(x); x = dpp_add<0x122>(x);
  x = dpp_add<0x124>(x); x = dpp_add<0x128>(x);
  return x;
}

//======================= Kernel 1: precompute Wt, c ================================
// [R3-validated, unchanged]
template<int K0>
__device__ __forceinline__ void gj_block(float rr[32], float* __restrict__ buf0,
                                         float* __restrict__ buf1,
                                         const int irow, const int qq) {
  const bool qsel = (qq == K0);
  #pragma unroll
  for (int kk = 0; kk < 32; kk++) {
    const int k = 32*K0 + kk;
    float* wb = ((kk & 1) == 0) ? buf0 : buf1;
    if (irow == k) {
      #pragma unroll
      for (int j4 = 0; j4 < 8; j4++)
        *(float4*)&wb[36*qq + 4*j4] = *(const float4*)&rr[4*j4];
    }
    __syncthreads();
    const float akk  = wb[36*K0 + kk];
    float pinv = __builtin_amdgcn_rcpf(akk);
    pinv = pinv + pinv*(1.0f - akk*pinv);
    constexpr int QP = K0 | (K0<<2) | (K0<<4) | (K0<<6);
    const int fi = __builtin_amdgcn_update_dpp(__float_as_int(rr[kk]),
                      __float_as_int(rr[kk]), QP, 0xF, 0xF, false);
    const float f = __int_as_float(fi);
    const bool piv = (irow == k);
    float gfac = f * pinv;
    gfac = piv ? (1.0f - pinv) : gfac;
    float rk[32];
    #pragma unroll
    for (int j4 = 0; j4 < 8; j4++)
      *(float4*)&rk[4*j4] = *(const float4*)&wb[36*qq + 4*j4];
    #pragma unroll
    for (int j = 0; j < 32; j++) rr[j] -= gfac * rk[j];
    const float pivfix = piv ? pinv : -gfac;
    if (qsel) rr[kk] = pivfix;
  }
}

__global__ void __launch_bounds__(512, 2)
precompute_kernel(const float* __restrict__ Pg, const float* __restrict__ qg,
                  const float* __restrict__ Ag, float* __restrict__ wsWt,
                  float* __restrict__ wsC)
{
  __shared__ float smem[16384];
  const int t = threadIdx.x;
  const int b = blockIdx.x;
  const float* __restrict__ Pb = Pg + (size_t)b*Nn*Nn;
  const float* __restrict__ qb = qg + (size_t)b*Nn;
  const float* __restrict__ Ab = Ag + (size_t)b*Mm*Nn;

  //---- Phase A: S = P + sigma*I + rho * A^T A ----
  {
    const int ar = t & 31;
    const int bc = t >> 5;
    float acc[4][8];
    #pragma unroll
    for (int a=0;a<4;a++)
      #pragma unroll
      for (int j=0;j<8;j++) acc[a][j]=0.f;

    for (int c=0;c<6;c++) {
      __syncthreads();
      {
        const float4* src = (const float4*)(Ab + c*32*Nn);
        float4* dst = (float4*)smem;
        dst[t]     = src[t];
        dst[t+512] = src[t+512];
      }
      __syncthreads();
      #pragma unroll 2
      for (int m=0;m<32;m++) {
        const float4 ra  = *(const float4*)&smem[m*Nn + 4*ar];
        const float4 cb0 = *(const float4*)&smem[m*Nn + 8*bc];
        const float4 cb1 = *(const float4*)&smem[m*Nn + 8*bc + 4];
        const float rv[4] = {ra.x, ra.y, ra.z, ra.w};
        const float cv[8] = {cb0.x,cb0.y,cb0.z,cb0.w,cb1.x,cb1.y,cb1.z,cb1.w};
        #pragma unroll
        for (int a=0;a<4;a++)
          #pragma unroll
          for (int j=0;j<8;j++) acc[a][j] += rv[a]*cv[j];
      }
    }
    __syncthreads();
    #pragma unroll
    for (int a=0;a<4;a++) {
      const int i = 4*ar + a;
      #pragma unroll
      for (int j=0;j<8;j++) {
        const int jj = 8*bc + j;
        float v = Pb[i*Nn + jj] + RHO_*acc[a][j];
        if (i == jj) v += SIGMA_;
        smem[i*Nn + jj] = v;
      }
    }
    __syncthreads();
  }

  //---- Phase B: Gauss-Jordan inverse ----
  {
    const int irow = t >> 2;
    const int qq   = t & 3;
    float rr[32];
    #pragma unroll
    for (int j=0;j<32;j++) rr[j] = smem[irow*Nn + 32*qq + j];
    __syncthreads();
    float* buf0 = smem;
    float* buf1 = smem + 144;
    gj_block<0>(rr, buf0, buf1, irow, qq);
    gj_block<1>(rr, buf0, buf1, irow, qq);
    gj_block<2>(rr, buf0, buf1, irow, qq);
    gj_block<3>(rr, buf0, buf1, irow, qq);
    __syncthreads();
    #pragma unroll
    for (int j=0;j<32;j++) smem[irow*Nn + 32*qq + j] = rr[j];
  }
  __syncthreads();

  //---- Phase C: Wt = A * Minv -> wsWt; c = Minv q -> wsC ----
  {
    const int jr = t & 63, kc = t >> 6;
    v2f acc[3][8];
    #pragma unroll
    for (int a=0;a<3;a++)
      #pragma unroll
      for (int p=0;p<8;p++) acc[a][p] = (v2f){0.f,0.f};

    for (int mi=0; mi<32; mi++) {
      const v4f a0 = *(const v4f*)&Ab[(jr      )*Nn + 4*mi];
      const v4f a1 = *(const v4f*)&Ab[(jr +  64)*Nn + 4*mi];
      const v4f a2 = *(const v4f*)&Ab[(jr + 128)*Nn + 4*mi];
      const float am[3][4] = {{a0.x,a0.y,a0.z,a0.w},
                              {a1.x,a1.y,a1.z,a1.w},
                              {a2.x,a2.y,a2.z,a2.w}};
      #pragma unroll
      for (int q=0;q<4;q++) {
        const int m = 4*mi + q;
        const v4f w0 = *(const v4f*)&smem[m*Nn + 16*kc +  0];
        const v4f w1 = *(const v4f*)&smem[m*Nn + 16*kc +  4];
        const v4f w2 = *(const v4f*)&smem[m*Nn + 16*kc +  8];
        const v4f w3 = *(const v4f*)&smem[m*Nn + 16*kc + 12];
        const v2f wp[8] = {(v2f){w0.x,w0.y},(v2f){w0.z,w0.w},
                           (v2f){w1.x,w1.y},(v2f){w1.z,w1.w},
                           (v2f){w2.x,w2.y},(v2f){w2.z,w2.w},
                           (v2f){w3.x,w3.y},(v2f){w3.z,w3.w}};
        #pragma unroll
        for (int a=0;a<3;a++) {
          const v2f amv = (v2f){am[a][q], am[a][q]};
          #pragma unroll
          for (int p=0;p<8;p++) acc[a][p] += amv * wp[p];
        }
      }
    }
    float* wb = wsWt + (size_t)b*Mm*Nn;
    #pragma unroll
    for (int a=0;a<3;a++) {
      const int j = jr + 64*a;
      #pragma unroll
      for (int x=0;x<4;x++) {
        *(float4*)&wb[j*Nn + 16*kc + 4*x] =
          make_float4(acc[a][2*x].x, acc[a][2*x].y, acc[a][2*x+1].x, acc[a][2*x+1].y);
      }
    }
  }
  if (t < Nn) {
    float cc = 0.f;
    #pragma unroll 4
    for (int k=0;k<Nn;k++) cc += smem[k*Nn + t] * qb[k];
    wsC[(size_t)b*Nn + t] = cc;
  }
}

//======================= Kernel 2: V-space ADMM loop ===============================
#define ABASE 0
#define WBASE 6912
__global__ void __launch_bounds__(1024, 4)
loop_kernel(const float* __restrict__ Ag, const float* __restrict__ lg,
            const float* __restrict__ ug, const float* __restrict__ wsWt,
            const float* __restrict__ wsC, float* __restrict__ outg)
{
  __shared__ float smem[13824];   // 54 KiB: A-tile[192][36] + Wt-tile[192][36]
  const int t = threadIdx.x, b = blockIdx.x;
  const int ig = t >> 4, cg = t & 15;
  const float* __restrict__ Ab = Ag   + (size_t)b*Mm*Nn;
  const float* __restrict__ Wb = wsWt + (size_t)b*Mm*Nn;
  const float* __restrict__ cb = wsC  + (size_t)b*Nn;

  const int  pm  = 64*cg + ig;          // producer row (cg<3)
  const bool isp = (cg < 3);

  // ---- d = A_pm . c ; bounds (producers) ----
  float dreg = 0.f, lreg = 0.f, ureg = 0.f;
  if (isp) {
    lreg = lg[(size_t)b*Mm + pm];
    ureg = ug[(size_t)b*Mm + pm];
    const float4* ar = (const float4*)(Ab + pm*Nn);
    const float4* cr = (const float4*)cb;
    #pragma unroll 4
    for (int k4=0;k4<32;k4++) {
      const float4 av = ar[k4], cv = cr[k4];
      dreg += av.x*cv.x + av.y*cv.y + av.z*cv.z + av.w*cv.w;
    }
  }

  // ---- prologue: V rows into regs.  V[i][cg+16jj] = dot(A_i, Wt_{cg+16jj}) ----
  v2f accv[3][12];
  #pragma unroll
  for (int a=0;a<3;a++)
    #pragma unroll
    for (int jj=0;jj<12;jj++) accv[a][jj] = (v2f){0.f,0.f};

  for (int kc=0; kc<4; kc++) {
    __syncthreads();
    {
      int x = t;
      {
        const int row = x>>3, c4 = x&7;
        *(float4*)&smem[ABASE + 36*row + 4*c4] = *(const float4*)&Ab[row*Nn + 32*kc + 4*c4];
        *(float4*)&smem[WBASE + 36*row + 4*c4] = *(const float4*)&Wb[row*Nn + 32*kc + 4*c4];
      }
      if (t < 512) {
        x = t + 1024;
        const int row = x>>3, c4 = x&7;
        *(float4*)&smem[ABASE + 36*row + 4*c4] = *(const float4*)&Ab[row*Nn + 32*kc + 4*c4];
        *(float4*)&smem[WBASE + 36*row + 4*c4] = *(const float4*)&Wb[row*Nn + 32*kc + 4*c4];
      }
    }
    __syncthreads();
    #pragma unroll
    for (int m4=0; m4<8; m4++) {
      const v4f a0 = *(const v4f*)&smem[ABASE + 36*(ig      ) + 4*m4];
      const v4f a1 = *(const v4f*)&smem[ABASE + 36*(ig +  64) + 4*m4];
      const v4f a2 = *(const v4f*)&smem[ABASE + 36*(ig + 128) + 4*m4];
      const v2f a0lo = (v2f){a0.x,a0.y}, a0hi = (v2f){a0.z,a0.w};
      const v2f a1lo = (v2f){a1.x,a1.y}, a1hi = (v2f){a1.z,a1.w};
      const v2f a2lo = (v2f){a2.x,a2.y}, a2hi = (v2f){a2.z,a2.w};
      #pragma unroll
      for (int jj=0; jj<12; jj++) {
        const v4f w = *(const v4f*)&smem[WBASE + 36*(cg + 16*jj) + 4*m4];
        const v2f wlo = (v2f){w.x,w.y}, whi = (v2f){w.z,w.w};
        accv[0][jj] = pk_fma(a0hi, whi, pk_fma(a0lo, wlo, accv[0][jj]));
        accv[1][jj] = pk_fma(a1hi, whi, pk_fma(a1lo, wlo, accv[1][jj]));
        accv[2][jj] = pk_fma(a2hi, whi, pk_fma(a2lo, wlo, accv[2][jj]));
      }
    }
  }
  // pack: Vp[a][jp] = {V[i][cg+16*(2jp)], V[i][cg+16*(2jp+1)]}
  v2f Vp[3][6];
  #pragma unroll
  for (int a=0;a<3;a++)
    #pragma unroll
    for (int jp=0;jp<6;jp++)
      Vp[a][jp] = (v2f){accv[a][2*jp].x + accv[a][2*jp].y,
                        accv[a][2*jp+1].x + accv[a][2*jp+1].y};

  __syncthreads();
  float* sT0  = smem;
  float* sT1  = smem + 192;
  float* sacc = smem + 384;
  if (t < Mm) sT0[t] = 0.f;
  __syncthreads();

  const int woff = (pm & 15)*12 + (pm >> 4);
  float sreg = 0.f, zreg = 0.f, yreg = 0.f, Sacc = 0.f;

#define ITER(RD, WR)                                                           \
  {                                                                            \
    const v4f sA = *(const v4f*)((RD) + 12*cg);                                \
    const v4f sB = *(const v4f*)((RD) + 12*cg + 4);                            \
    const v4f sC = *(const v4f*)((RD) + 12*cg + 8);                            \
    const v2f s0 = (v2f){sA.x,sA.y}, s1 = (v2f){sA.z,sA.w};                    \
    const v2f s2 = (v2f){sB.x,sB.y}, s3 = (v2f){sB.z,sB.w};                    \
    const v2f s4 = (v2f){sC.x,sC.y}, s5 = (v2f){sC.z,sC.w};                    \
    v2f t0 = pk_mul(Vp[0][0], s0);                                             \
    v2f t1 = pk_mul(Vp[1][0], s0);                                             \
    v2f t2 = pk_mul(Vp[2][0], s0);                                             \
    t0 = pk_fma(Vp[0][1], s1, t0); t1 = pk_fma(Vp[1][1], s1, t1);              \
    t2 = pk_fma(Vp[2][1], s1, t2);                                             \
    t0 = pk_fma(Vp[0][2], s2, t0); t1 = pk_fma(Vp[1][2], s2, t1);              \
    t2 = pk_fma(Vp[2][2], s2, t2);                                             \
    t0 = pk_fma(Vp[0][3], s3, t0); t1 = pk_fma(Vp[1][3], s3, t1);              \
    t2 = pk_fma(Vp[2][3], s3, t2);                                             \
    t0 = pk_fma(Vp[0][4], s4, t0); t1 = pk_fma(Vp[1][4], s4, t1);              \
    t2 = pk_fma(Vp[2][4], s4, t2);                                             \
    t0 = pk_fma(Vp[0][5], s5, t0); t1 = pk_fma(Vp[1][5], s5, t1);              \
    t2 = pk_fma(Vp[2][5], s5, t2);                                             \
    float r0 = t0.x + t0.y, r1 = t1.x + t1.y, r2 = t2.x + t2.y;                \
    r0 = red16(r0); r1 = red16(r1); r2 = red16(r2);                            \
    if (isp) {                                                                 \
      const float w  = ((cg==0) ? r0 : (cg==1) ? r1 : r2) - dreg;              \
      const float zc = ALPHA_*w + (1.f-ALPHA_)*zreg;                           \
      const float vv = zc + yreg*RHOINV_;                                      \
      const float zn = fminf(fmaxf(vv, lreg), ureg);                           \
      const float sn = RHO_*(zn + zn - vv);                                    \
      (WR)[woff] = sn;                /* write ASAP; updates below off-path */ \
      yreg = RHO_*(vv - zn);                                                   \
      zreg = zn;                                                               \
      Sacc = (1.f-ALPHA_)*Sacc + ALPHA_*sreg;                                  \
      sreg = sn;                                                               \
    }                                                                          \
    __syncthreads();                                                           \
  }

  #pragma unroll 1
  for (int it2 = 0; it2 < NITERS_/2; it2++) {
    ITER(sT0, sT1)
    ITER(sT1, sT0)
  }
#undef ITER

  // ---- epilogue: x = Wt^T Sacc - c ----
  if (isp) sacc[pm] = Sacc;
  __syncthreads();
  if (t < Nn) {
    float acc = -cb[t];
    #pragma unroll 4
    for (int j=0;j<Mm;j++) acc += Wb[j*Nn + t] * sacc[j];
    outg[(size_t)b*Nn + t] = acc;
  }
}

extern "C" void kernel_launch(void* const* d_in, const int* in_sizes, int n_in,
                              void* d_out, int out_size, void* d_ws, size_t ws_size,
                              hipStream_t stream) {
  const float* P = (const float*)d_in[0];
  const float* q = (const float*)d_in[1];
  const float* A = (const float*)d_in[2];
  const float* l = (const float*)d_in[3];
  const float* u = (const float*)d_in[4];
  (void)in_sizes; (void)n_in; (void)out_size; (void)ws_size;
  float* wsWt = (float*)d_ws;                      // 256*192*128 floats = 25.2 MB
  float* wsC  = wsWt + (size_t)256*Mm*Nn;          // 256*128 floats
  precompute_kernel<<<256, 512, 0, stream>>>(P, q, A, wsWt, wsC);
  loop_kernel<<<256, 1024, 0, stream>>>(A, l, u, wsWt, wsC, (float*)d_out);
}

// Round 5
// 437.896 us; speedup vs baseline: 1.1640x; 1.1640x over previous
//
#include <hip/hip_runtime.h>

// OSQP batched ADMM, B=256 N=128 M=192, 400 iters.
// R5: R3 structure restored (R4's inline-asm pk_fma regressed: compiler copies
// + scheduling barriers). Loop kernel now pure scalar FMA + fused DPP + short
// p-state producer tail.
// Algebra: M = P + sI + rho*AtA (SPD);  Wt = A*Minv;  c = Minv q
//   V = A Minv At;  d = A c
//   iterate (s_0=0), state (p = (1-a)z + y/rho, s, Sacc):
//     r = V s ; w = r - d ; v = a*w + p ; z = med3(v,l,u) ;
//     s' = rho*(2z - v) ; Sacc' = (1-a)Sacc + a*s ; p' = v - a*z
//   epilogue: x = Wt^T Sacc - c

#define Nn 128
#define Mm 192
constexpr float RHO_    = 0.1f;
constexpr float RHOINV_ = 10.0f;
constexpr float SIGMA_  = 1e-6f;
constexpr float ALPHA_  = 1.6f;
constexpr int   NITERS_ = 400;

typedef float v2f __attribute__((ext_vector_type(2)));
typedef float v4f __attribute__((ext_vector_type(4)));

template<int CTRL>
__device__ __forceinline__ float dpp_add(float x) {
  // old = x so GCNDPPCombine can fold to v_add_f32_dpp (no zero-init mov)
  int y = __builtin_amdgcn_update_dpp(__float_as_int(x), __float_as_int(x),
                                      CTRL, 0xF, 0xF, false);
  return x + __int_as_float(y);
}
// sum across aligned 16-lane group: row_ror 1,2,4,8 (all lanes end with total)
__device__ __forceinline__ float red16(float x) {
  x = dpp_add<0x121>(x); x = dpp_add<0x122>(x);
  x = dpp_add<0x124>(x); x = dpp_add<0x128>(x);
  return x;
}

//======================= Kernel 1: precompute Wt, c ================================
// [R3-validated, unchanged]
template<int K0>
__device__ __forceinline__ void gj_block(float rr[32], float* __restrict__ buf0,
                                         float* __restrict__ buf1,
                                         const int irow, const int qq) {
  const bool qsel = (qq == K0);
  #pragma unroll
  for (int kk = 0; kk < 32; kk++) {
    const int k = 32*K0 + kk;
    float* wb = ((kk & 1) == 0) ? buf0 : buf1;
    if (irow == k) {
      #pragma unroll
      for (int j4 = 0; j4 < 8; j4++)
        *(float4*)&wb[36*qq + 4*j4] = *(const float4*)&rr[4*j4];
    }
    __syncthreads();
    const float akk  = wb[36*K0 + kk];
    float pinv = __builtin_amdgcn_rcpf(akk);
    pinv = pinv + pinv*(1.0f - akk*pinv);
    constexpr int QP = K0 | (K0<<2) | (K0<<4) | (K0<<6);
    const int fi = __builtin_amdgcn_update_dpp(__float_as_int(rr[kk]),
                      __float_as_int(rr[kk]), QP, 0xF, 0xF, false);
    const float f = __int_as_float(fi);
    const bool piv = (irow == k);
    float gfac = f * pinv;
    gfac = piv ? (1.0f - pinv) : gfac;
    float rk[32];
    #pragma unroll
    for (int j4 = 0; j4 < 8; j4++)
      *(float4*)&rk[4*j4] = *(const float4*)&wb[36*qq + 4*j4];
    #pragma unroll
    for (int j = 0; j < 32; j++) rr[j] -= gfac * rk[j];
    const float pivfix = piv ? pinv : -gfac;
    if (qsel) rr[kk] = pivfix;
  }
}

__global__ void __launch_bounds__(512, 2)
precompute_kernel(const float* __restrict__ Pg, const float* __restrict__ qg,
                  const float* __restrict__ Ag, float* __restrict__ wsWt,
                  float* __restrict__ wsC)
{
  __shared__ float smem[16384];
  const int t = threadIdx.x;
  const int b = blockIdx.x;
  const float* __restrict__ Pb = Pg + (size_t)b*Nn*Nn;
  const float* __restrict__ qb = qg + (size_t)b*Nn;
  const float* __restrict__ Ab = Ag + (size_t)b*Mm*Nn;

  //---- Phase A: S = P + sigma*I + rho * A^T A ----
  {
    const int ar = t & 31;
    const int bc = t >> 5;
    float acc[4][8];
    #pragma unroll
    for (int a=0;a<4;a++)
      #pragma unroll
      for (int j=0;j<8;j++) acc[a][j]=0.f;

    for (int c=0;c<6;c++) {
      __syncthreads();
      {
        const float4* src = (const float4*)(Ab + c*32*Nn);
        float4* dst = (float4*)smem;
        dst[t]     = src[t];
        dst[t+512] = src[t+512];
      }
      __syncthreads();
      #pragma unroll 2
      for (int m=0;m<32;m++) {
        const float4 ra  = *(const float4*)&smem[m*Nn + 4*ar];
        const float4 cb0 = *(const float4*)&smem[m*Nn + 8*bc];
        const float4 cb1 = *(const float4*)&smem[m*Nn + 8*bc + 4];
        const float rv[4] = {ra.x, ra.y, ra.z, ra.w};
        const float cv[8] = {cb0.x,cb0.y,cb0.z,cb0.w,cb1.x,cb1.y,cb1.z,cb1.w};
        #pragma unroll
        for (int a=0;a<4;a++)
          #pragma unroll
          for (int j=0;j<8;j++) acc[a][j] += rv[a]*cv[j];
      }
    }
    __syncthreads();
    #pragma unroll
    for (int a=0;a<4;a++) {
      const int i = 4*ar + a;
      #pragma unroll
      for (int j=0;j<8;j++) {
        const int jj = 8*bc + j;
        float v = Pb[i*Nn + jj] + RHO_*acc[a][j];
        if (i == jj) v += SIGMA_;
        smem[i*Nn + jj] = v;
      }
    }
    __syncthreads();
  }

  //---- Phase B: Gauss-Jordan inverse ----
  {
    const int irow = t >> 2;
    const int qq   = t & 3;
    float rr[32];
    #pragma unroll
    for (int j=0;j<32;j++) rr[j] = smem[irow*Nn + 32*qq + j];
    __syncthreads();
    float* buf0 = smem;
    float* buf1 = smem + 144;
    gj_block<0>(rr, buf0, buf1, irow, qq);
    gj_block<1>(rr, buf0, buf1, irow, qq);
    gj_block<2>(rr, buf0, buf1, irow, qq);
    gj_block<3>(rr, buf0, buf1, irow, qq);
    __syncthreads();
    #pragma unroll
    for (int j=0;j<32;j++) smem[irow*Nn + 32*qq + j] = rr[j];
  }
  __syncthreads();

  //---- Phase C: Wt = A * Minv -> wsWt; c = Minv q -> wsC ----
  {
    const int jr = t & 63, kc = t >> 6;
    v2f acc[3][8];
    #pragma unroll
    for (int a=0;a<3;a++)
      #pragma unroll
      for (int p=0;p<8;p++) acc[a][p] = (v2f){0.f,0.f};

    for (int mi=0; mi<32; mi++) {
      const v4f a0 = *(const v4f*)&Ab[(jr      )*Nn + 4*mi];
      const v4f a1 = *(const v4f*)&Ab[(jr +  64)*Nn + 4*mi];
      const v4f a2 = *(const v4f*)&Ab[(jr + 128)*Nn + 4*mi];
      const float am[3][4] = {{a0.x,a0.y,a0.z,a0.w},
                              {a1.x,a1.y,a1.z,a1.w},
                              {a2.x,a2.y,a2.z,a2.w}};
      #pragma unroll
      for (int q=0;q<4;q++) {
        const int m = 4*mi + q;
        const v4f w0 = *(const v4f*)&smem[m*Nn + 16*kc +  0];
        const v4f w1 = *(const v4f*)&smem[m*Nn + 16*kc +  4];
        const v4f w2 = *(const v4f*)&smem[m*Nn + 16*kc +  8];
        const v4f w3 = *(const v4f*)&smem[m*Nn + 16*kc + 12];
        const v2f wp[8] = {(v2f){w0.x,w0.y},(v2f){w0.z,w0.w},
                           (v2f){w1.x,w1.y},(v2f){w1.z,w1.w},
                           (v2f){w2.x,w2.y},(v2f){w2.z,w2.w},
                           (v2f){w3.x,w3.y},(v2f){w3.z,w3.w}};
        #pragma unroll
        for (int a=0;a<3;a++) {
          const v2f amv = (v2f){am[a][q], am[a][q]};
          #pragma unroll
          for (int p=0;p<8;p++) acc[a][p] += amv * wp[p];
        }
      }
    }
    float* wb = wsWt + (size_t)b*Mm*Nn;
    #pragma unroll
    for (int a=0;a<3;a++) {
      const int j = jr + 64*a;
      #pragma unroll
      for (int x=0;x<4;x++) {
        *(float4*)&wb[j*Nn + 16*kc + 4*x] =
          make_float4(acc[a][2*x].x, acc[a][2*x].y, acc[a][2*x+1].x, acc[a][2*x+1].y);
      }
    }
  }
  if (t < Nn) {
    float cc = 0.f;
    #pragma unroll 4
    for (int k=0;k<Nn;k++) cc += smem[k*Nn + t] * qb[k];
    wsC[(size_t)b*Nn + t] = cc;
  }
}

//======================= Kernel 2: V-space ADMM loop ===============================
#define ABASE 0
#define WBASE 6912
__global__ void __launch_bounds__(1024, 4)
loop_kernel(const float* __restrict__ Ag, const float* __restrict__ lg,
            const float* __restrict__ ug, const float* __restrict__ wsWt,
            const float* __restrict__ wsC, float* __restrict__ outg)
{
  __shared__ float smem[13824];   // 54 KiB: A-tile[192][36] + Wt-tile[192][36]
  const int t = threadIdx.x, b = blockIdx.x;
  const int ig = t >> 4, cg = t & 15;
  const float* __restrict__ Ab = Ag   + (size_t)b*Mm*Nn;
  const float* __restrict__ Wb = wsWt + (size_t)b*Mm*Nn;
  const float* __restrict__ cb = wsC  + (size_t)b*Nn;

  const int  pm  = 64*cg + ig;          // producer row (cg<3)
  const bool isp = (cg < 3);

  // ---- d = A_pm . c ; bounds (producers) ----
  float dreg = 0.f, lreg = 0.f, ureg = 0.f;
  if (isp) {
    lreg = lg[(size_t)b*Mm + pm];
    ureg = ug[(size_t)b*Mm + pm];
    const float4* ar = (const float4*)(Ab + pm*Nn);
    const float4* cr = (const float4*)cb;
    #pragma unroll 4
    for (int k4=0;k4<32;k4++) {
      const float4 av = ar[k4], cv = cr[k4];
      dreg += av.x*cv.x + av.y*cv.y + av.z*cv.z + av.w*cv.w;
    }
  }

  // ---- prologue: V rows into regs.  V[i][cg+16jj] = dot(A_i, Wt_{cg+16jj}) ----
  // [R3 form — plain C, no asm]
  v2f accv[3][12];
  #pragma unroll
  for (int a=0;a<3;a++)
    #pragma unroll
    for (int jj=0;jj<12;jj++) accv[a][jj] = (v2f){0.f,0.f};

  for (int kc=0; kc<4; kc++) {
    __syncthreads();
    {
      int x = t;
      {
        const int row = x>>3, c4 = x&7;
        *(float4*)&smem[ABASE + 36*row + 4*c4] = *(const float4*)&Ab[row*Nn + 32*kc + 4*c4];
        *(float4*)&smem[WBASE + 36*row + 4*c4] = *(const float4*)&Wb[row*Nn + 32*kc + 4*c4];
      }
      if (t < 512) {
        x = t + 1024;
        const int row = x>>3, c4 = x&7;
        *(float4*)&smem[ABASE + 36*row + 4*c4] = *(const float4*)&Ab[row*Nn + 32*kc + 4*c4];
        *(float4*)&smem[WBASE + 36*row + 4*c4] = *(const float4*)&Wb[row*Nn + 32*kc + 4*c4];
      }
    }
    __syncthreads();
    #pragma unroll
    for (int m4=0; m4<8; m4++) {
      const v4f a0 = *(const v4f*)&smem[ABASE + 36*(ig      ) + 4*m4];
      const v4f a1 = *(const v4f*)&smem[ABASE + 36*(ig +  64) + 4*m4];
      const v4f a2 = *(const v4f*)&smem[ABASE + 36*(ig + 128) + 4*m4];
      #pragma unroll
      for (int jj=0; jj<12; jj++) {
        const v4f w = *(const v4f*)&smem[WBASE + 36*(cg + 16*jj) + 4*m4];
        const v2f wlo = (v2f){w.x,w.y}, whi = (v2f){w.z,w.w};
        accv[0][jj] += (v2f){a0.x,a0.y}*wlo + (v2f){a0.z,a0.w}*whi;
        accv[1][jj] += (v2f){a1.x,a1.y}*wlo + (v2f){a1.z,a1.w}*whi;
        accv[2][jj] += (v2f){a2.x,a2.y}*wlo + (v2f){a2.z,a2.w}*whi;
      }
    }
  }
  // reduce v2f partials to scalar V rows
  float Vr[3][12];
  #pragma unroll
  for (int a=0;a<3;a++)
    #pragma unroll
    for (int jj=0;jj<12;jj++)
      Vr[a][jj] = accv[a][jj].x + accv[a][jj].y;

  __syncthreads();
  float* sT0  = smem;
  float* sT1  = smem + 192;
  float* sacc = smem + 384;
  if (t < Mm) sT0[t] = 0.f;
  __syncthreads();

  const int woff = (pm & 15)*12 + (pm >> 4);
  // state: p = (1-a)z + y/rho (0 at start), s, Sacc
  float sreg = 0.f, preg = 0.f, Sacc = 0.f;
  const float* sR0 = sT0 + 12*cg;
  const float* sR1 = sT1 + 12*cg;

#define ITER(RD, WR)                                                           \
  {                                                                            \
    const float4 sA = *(const float4*)(RD);                                    \
    const float4 sB = *(const float4*)((RD) + 4);                              \
    const float4 sC = *(const float4*)((RD) + 8);                              \
    float r0 = Vr[0][0]*sA.x + Vr[0][1]*sA.y + Vr[0][2]*sA.z + Vr[0][3]*sA.w   \
             + Vr[0][4]*sB.x + Vr[0][5]*sB.y + Vr[0][6]*sB.z + Vr[0][7]*sB.w   \
             + Vr[0][8]*sC.x + Vr[0][9]*sC.y + Vr[0][10]*sC.z + Vr[0][11]*sC.w;\
    float r1 = Vr[1][0]*sA.x + Vr[1][1]*sA.y + Vr[1][2]*sA.z + Vr[1][3]*sA.w   \
             + Vr[1][4]*sB.x + Vr[1][5]*sB.y + Vr[1][6]*sB.z + Vr[1][7]*sB.w   \
             + Vr[1][8]*sC.x + Vr[1][9]*sC.y + Vr[1][10]*sC.z + Vr[1][11]*sC.w;\
    float r2 = Vr[2][0]*sA.x + Vr[2][1]*sA.y + Vr[2][2]*sA.z + Vr[2][3]*sA.w   \
             + Vr[2][4]*sB.x + Vr[2][5]*sB.y + Vr[2][6]*sB.z + Vr[2][7]*sB.w   \
             + Vr[2][8]*sC.x + Vr[2][9]*sC.y + Vr[2][10]*sC.z + Vr[2][11]*sC.w;\
    r0 = red16(r0); r1 = red16(r1); r2 = red16(r2);                            \
    if (isp) {                                                                 \
      const float r  = (cg==0) ? r0 : ((cg==1) ? r1 : r2);                     \
      const float w  = r - dreg;                                               \
      const float v  = fmaf(ALPHA_, w, preg);                                  \
      const float z  = __builtin_amdgcn_fmed3f(v, lreg, ureg);                 \
      const float sn = RHO_ * fmaf(2.0f, z, -v);                               \
      (WR)[woff] = sn;                                                         \
      Sacc = (1.f-ALPHA_)*Sacc + ALPHA_*sreg;                                  \
      sreg = sn;                                                               \
      preg = fmaf(-ALPHA_, z, v);                                              \
    }                                                                          \
    __syncthreads();                                                           \
  }

  #pragma unroll 1
  for (int it2 = 0; it2 < NITERS_/2; it2++) {
    ITER(sR0, sT1)
    ITER(sR1, sT0)
  }
#undef ITER

  // ---- epilogue: x = Wt^T Sacc - c ----
  if (isp) sacc[pm] = Sacc;
  __syncthreads();
  if (t < Nn) {
    float acc = -cb[t];
    #pragma unroll 4
    for (int j=0;j<Mm;j++) acc += Wb[j*Nn + t] * sacc[j];
    outg[(size_t)b*Nn + t] = acc;
  }
}

extern "C" void kernel_launch(void* const* d_in, const int* in_sizes, int n_in,
                              void* d_out, int out_size, void* d_ws, size_t ws_size,
                              hipStream_t stream) {
  const float* P = (const float*)d_in[0];
  const float* q = (const float*)d_in[1];
  const float* A = (const float*)d_in[2];
  const float* l = (const float*)d_in[3];
  const float* u = (const float*)d_in[4];
  (void)in_sizes; (void)n_in; (void)out_size; (void)ws_size;
  float* wsWt = (float*)d_ws;                      // 256*192*128 floats = 25.2 MB
  float* wsC  = wsWt + (size_t)256*Mm*Nn;          // 256*128 floats
  precompute_kernel<<<256, 512, 0, stream>>>(P, q, A, wsWt, wsC);
  loop_kernel<<<256, 1024, 0, stream>>>(A, l, u, wsWt, wsC, (float*)d_out);
}